// Round 1
// baseline (503.951 us; speedup 1.0000x reference)
//
#include <hip/hip_runtime.h>
#include <cstdint>
#include <cstddef>

#define EPSV 1e-5f

typedef __bf16 bf16x8 __attribute__((ext_vector_type(8)));
typedef float f32x4 __attribute__((ext_vector_type(4)));

__device__ __forceinline__ unsigned short f2bf(float f) {
  unsigned int u = __float_as_uint(f);
  u += 0x7FFFu + ((u >> 16) & 1u);   // round-to-nearest-even
  return (unsigned short)(u >> 16);
}

__device__ __forceinline__ void async_copy16(const void* src, void* dst_lds) {
  __builtin_amdgcn_global_load_lds(
      (const __attribute__((address_space(1))) void*)src,
      (__attribute__((address_space(3))) void*)dst_lds, 16, 0, 0);
}

// ---------------- Kernel 1: feat_global = mean(x_global, hw) + BN ----------
__global__ __launch_bounds__(256) void kmean(
    const float* __restrict__ x, const float* __restrict__ g,
    const float* __restrict__ bb, const float* __restrict__ rm,
    const float* __restrict__ rv, float* __restrict__ out) {
  int gw = blockIdx.x * 4 + (threadIdx.x >> 6);   // (b,c) pair per wave
  int lane = threadIdx.x & 63;
  float4 v = ((const float4*)(x + (size_t)gw * 256))[lane];
  float s = v.x + v.y + v.z + v.w;
#pragma unroll
  for (int o = 32; o > 0; o >>= 1) s += __shfl_xor(s, o, 64);
  if (lane == 0) {
    int b = gw >> 11, c = gw & 2047;
    float m = s * (1.f / 256.f);
    out[(size_t)b * 43008 + c] =
        (m - rm[c]) / sqrtf(rv[c] + EPSV) * g[c] + bb[c];
  }
}

// ---------------- Kernel 2: mask downsample, counts, drop ------------------
__global__ __launch_bounds__(256) void kmask(
    const int* __restrict__ mask, int* __restrict__ partid,
    float* __restrict__ invden, int* __restrict__ dropm1) {
  int b = blockIdx.x;
  int t = threadIdx.x;
  int h = t >> 4, w = t & 15;
  int m = mask[(size_t)b * 65536 + h * 4096 + w * 16];  // [b,0,h*16,w*16]
  partid[b * 256 + t] = m;
  __shared__ int cnt[10];
  if (t < 10) cnt[t] = 0;
  __syncthreads();
  atomicAdd(&cnt[m], 1);
  __syncthreads();
  if (t == 0) {
    int dp = 0;  // argmax(counts>0); all-false -> 0
    for (int p = 8; p >= 0; p--)
      if (cnt[p + 1] > 0) dp = p;
    dropm1[b] = dp;
  }
  if (t < 9) invden[b * 9 + t] = 1.f / ((float)cnt[t + 1] + 1e-8f);
}

// ---------------- Kernel 3: part-pooling -> A (bf16, both branches) --------
// self_feat == mask_feat with row (drop-1) zeroed.
__global__ __launch_bounds__(256) void kpool(
    const float* __restrict__ x, const int* __restrict__ partid,
    const float* __restrict__ invden, const int* __restrict__ dropm1,
    unsigned short* __restrict__ Abuf) {
  int gw = blockIdx.x * 4 + (threadIdx.x >> 6);  // (b,c) per wave
  int lane = threadIdx.x & 63;
  int b = gw >> 11, c = gw & 2047;
  int4 pid = ((const int4*)(partid + b * 256))[lane];
  float4 v = ((const float4*)(x + (size_t)gw * 256))[lane];
  float acc[9];
#pragma unroll
  for (int p = 0; p < 9; p++) acc[p] = 0.f;
#pragma unroll
  for (int p = 0; p < 9; p++) {
    acc[p] += (pid.x == p + 1) ? v.x : 0.f;
    acc[p] += (pid.y == p + 1) ? v.y : 0.f;
    acc[p] += (pid.z == p + 1) ? v.z : 0.f;
    acc[p] += (pid.w == p + 1) ? v.w : 0.f;
  }
#pragma unroll
  for (int p = 0; p < 9; p++) {
    float s = acc[p];
#pragma unroll
    for (int o = 32; o > 0; o >>= 1) s += __shfl_xor(s, o, 64);
    acc[p] = s;
  }
  if (lane == 0) {
    int dm1 = dropm1[b];
#pragma unroll
    for (int p = 0; p < 9; p++) {
      float val = acc[p] * invden[b * 9 + p];
      unsigned short h = f2bf(val);
      Abuf[(size_t)(b * 9 + p) * 2048 + c] = h;
      Abuf[(size_t)((64 + b) * 9 + p) * 2048 + c] =
          (p == dm1) ? (unsigned short)0 : h;
    }
  }
}

// ---------------- Kernel 4: W (KxN fp32) -> Wt (NxK bf16) ------------------
__global__ __launch_bounds__(256) void ktranspose(
    const float* __restrict__ W, unsigned short* __restrict__ Wt) {
  __shared__ float tile[32][33];
  int tx = threadIdx.x & 31;
  int ty = threadIdx.x >> 5;  // 0..7
  int k0 = blockIdx.y * 32;
  int n0 = blockIdx.x * 32;
#pragma unroll
  for (int i = 0; i < 32; i += 8)
    tile[ty + i][tx] = W[(size_t)(k0 + ty + i) * 2048 + n0 + tx];
  __syncthreads();
#pragma unroll
  for (int i = 0; i < 32; i += 8)
    Wt[(size_t)(n0 + ty + i) * 2048 + k0 + tx] = f2bf(tile[tx][ty + i]);
}

// ---------------- GEMM: S[M,N] = A[M,K] @ Wt[N,K]^T  (bf16 MFMA) -----------
// M=1152, N=K=2048.  128x128 tile, BK=32, 4 waves of 64x64.
#define GK 2048
__global__ __launch_bounds__(256) void gemm_bf16(
    const unsigned short* __restrict__ A, const unsigned short* __restrict__ Bt,
    float* __restrict__ S) {
  __shared__ unsigned short As[128 * 32];
  __shared__ unsigned short Bs[128 * 32];
  const int tid = threadIdx.x;
  const int lane = tid & 63;
  const int wave = tid >> 6;
  const int wm = (wave >> 1) << 6;
  const int wn = (wave & 1) << 6;
  const int quad = lane >> 4;
  const int l16 = lane & 15;
  const int by = blockIdx.y;
  const int bx = blockIdx.x;

  const unsigned short* Ag = A + (size_t)by * 128 * GK;
  const unsigned short* Bg = Bt + (size_t)bx * 128 * GK;

  f32x4 acc[4][4];
#pragma unroll
  for (int i = 0; i < 4; i++)
#pragma unroll
    for (int j = 0; j < 4; j++) acc[i][j] = (f32x4){0.f, 0.f, 0.f, 0.f};

  const int seg0 = tid, seg1 = tid + 256;
  const int r0 = seg0 >> 2, c0 = (seg0 & 3) * 8;
  const int r1 = seg1 >> 2, c1 = (seg1 & 3) * 8;

  for (int kk = 0; kk < GK; kk += 32) {
    __syncthreads();  // prev iter's LDS reads done
    async_copy16(Ag + (size_t)r0 * GK + kk + c0, &As[seg0 * 8]);
    async_copy16(Ag + (size_t)r1 * GK + kk + c1, &As[seg1 * 8]);
    async_copy16(Bg + (size_t)r0 * GK + kk + c0, &Bs[seg0 * 8]);
    async_copy16(Bg + (size_t)r1 * GK + kk + c1, &Bs[seg1 * 8]);
    asm volatile("s_waitcnt vmcnt(0)" ::: "memory");
    __syncthreads();

    bf16x8 af[4], bfr[4];
#pragma unroll
    for (int i = 0; i < 4; i++)
      af[i] = *(const bf16x8*)&As[(wm + i * 16 + l16) * 32 + quad * 8];
#pragma unroll
    for (int j = 0; j < 4; j++)
      bfr[j] = *(const bf16x8*)&Bs[(wn + j * 16 + l16) * 32 + quad * 8];
#pragma unroll
    for (int i = 0; i < 4; i++)
#pragma unroll
      for (int j = 0; j < 4; j++)
        acc[i][j] = __builtin_amdgcn_mfma_f32_16x16x32_bf16(af[i], bfr[j],
                                                            acc[i][j], 0, 0, 0);
  }

#pragma unroll
  for (int i = 0; i < 4; i++)
#pragma unroll
    for (int j = 0; j < 4; j++)
#pragma unroll
      for (int r = 0; r < 4; r++) {
        int m = by * 128 + wm + i * 16 + quad * 4 + r;
        int n = bx * 128 + wn + j * 16 + l16;
        S[(size_t)m * 2048 + n] = acc[i][j][r];
      }
}

// ---------------- Epilogue 1: adj-mix + bias + BN + ReLU -> A2 (bf16) ------
__global__ __launch_bounds__(256) void epi_mid(
    const float* __restrict__ S, const float* __restrict__ adj,
    const float* __restrict__ bias, const float* __restrict__ g,
    const float* __restrict__ be, const float* __restrict__ rm,
    const float* __restrict__ rv, unsigned short* __restrict__ Aout) {
  int idx = blockIdx.x * 256 + threadIdx.x;  // over 128*2048
  int d = idx & 2047;
  int bb = idx >> 11;
  int b = bb & 63;
  float s[9];
#pragma unroll
  for (int q = 0; q < 9; q++) s[q] = S[(size_t)(bb * 9 + q) * 2048 + d];
#pragma unroll
  for (int p = 0; p < 9; p++) {
    float o = bias[d];
#pragma unroll
    for (int q = 0; q < 9; q++) o += adj[b * 81 + p * 9 + q] * s[q];
    int f = p * 2048 + d;
    float v = (o - rm[f]) / sqrtf(rv[f] + EPSV) * g[f] + be[f];
    v = fmaxf(v, 0.f);
    Aout[(size_t)(bb * 9 + p) * 2048 + d] = f2bf(v);
  }
}

// ---------------- Epilogue 2: adj-mix + BN + ReLU -> cats, means, BN -------
__global__ __launch_bounds__(256) void epi_final(
    const float* __restrict__ S, const float* __restrict__ adj,
    const float* __restrict__ bias, const float* __restrict__ g,
    const float* __restrict__ be, const float* __restrict__ rm,
    const float* __restrict__ rv, const float* __restrict__ gn_g,
    const float* __restrict__ gn_b, const float* __restrict__ gn_rm,
    const float* __restrict__ gn_rv, float* __restrict__ out) {
  int idx = blockIdx.x * 256 + threadIdx.x;
  int d = idx & 2047;
  int bb = idx >> 11;
  int b = bb & 63;
  bool selfb = bb >= 64;
  float s[9];
#pragma unroll
  for (int q = 0; q < 9; q++) s[q] = S[(size_t)(bb * 9 + q) * 2048 + d];
  float* orow = out + (size_t)b * 43008;
  size_t catbase = selfb ? 24576 : 6144;
  float mean = 0.f;
#pragma unroll
  for (int p = 0; p < 9; p++) {
    float o = bias[d];
#pragma unroll
    for (int q = 0; q < 9; q++) o += adj[b * 81 + p * 9 + q] * s[q];
    int f = p * 2048 + d;
    float v = (o - rm[f]) / sqrtf(rv[f] + EPSV) * g[f] + be[f];
    v = fmaxf(v, 0.f);
    mean += v;
    orow[catbase + f] = v;
  }
  mean *= (1.f / 9.f);
  orow[(selfb ? 4096 : 2048) + d] =
      (mean - gn_rm[d]) / sqrtf(gn_rv[d] + EPSV) * gn_g[d] + gn_b[d];
}

extern "C" void kernel_launch(void* const* d_in, const int* in_sizes, int n_in,
                              void* d_out, int out_size, void* d_ws,
                              size_t ws_size, hipStream_t stream) {
  const float* x_global = (const float*)d_in[0];
  const float* x_gcn = (const float*)d_in[1];
  const int* mask = (const int*)d_in[2];
  const float* adj = (const float*)d_in[3];
  const float* W1 = (const float*)d_in[4];
  const float* b1 = (const float*)d_in[5];
  const float* g1 = (const float*)d_in[6];
  const float* be1 = (const float*)d_in[7];
  const float* rm1 = (const float*)d_in[8];
  const float* rv1 = (const float*)d_in[9];
  const float* W2 = (const float*)d_in[10];
  const float* b2 = (const float*)d_in[11];
  const float* g2 = (const float*)d_in[12];
  const float* be2 = (const float*)d_in[13];
  const float* rm2 = (const float*)d_in[14];
  const float* rv2 = (const float*)d_in[15];
  const float* gb_g = (const float*)d_in[16];
  const float* gb_b = (const float*)d_in[17];
  const float* gb_rm = (const float*)d_in[18];
  const float* gb_rv = (const float*)d_in[19];
  const float* gn_g = (const float*)d_in[20];
  const float* gn_b = (const float*)d_in[21];
  const float* gn_rm = (const float*)d_in[22];
  const float* gn_rv = (const float*)d_in[23];
  float* out = (float*)d_out;

  char* ws = (char*)d_ws;
  int* partid = (int*)(ws);                       // 64*256*4      = 65536
  float* invden = (float*)(ws + 65536);           // 576*4         = 2304
  int* dropm1 = (int*)(ws + 67840);               // 64*4
  unsigned short* Abuf = (unsigned short*)(ws + 131072);         // 1152*2048*2
  unsigned short* Wt1 = (unsigned short*)(ws + 131072 + 4718592);  // 8MB
  unsigned short* Wt2 =
      (unsigned short*)(ws + 131072 + 4718592 + 8388608);          // 8MB
  float* S = (float*)(ws + 131072 + 4718592 + 2 * 8388608);        // 9MB

  ktranspose<<<dim3(64, 64), 256, 0, stream>>>(W1, Wt1);
  ktranspose<<<dim3(64, 64), 256, 0, stream>>>(W2, Wt2);
  kmean<<<32768, 256, 0, stream>>>(x_global, gb_g, gb_b, gb_rm, gb_rv, out);
  kmask<<<64, 256, 0, stream>>>(mask, partid, invden, dropm1);
  kpool<<<32768, 256, 0, stream>>>(x_gcn, partid, invden, dropm1, Abuf);
  gemm_bf16<<<dim3(16, 9), 256, 0, stream>>>(Abuf, Wt1, S);
  epi_mid<<<1024, 256, 0, stream>>>(S, adj, b1, g1, be1, rm1, rv1, Abuf);
  gemm_bf16<<<dim3(16, 9), 256, 0, stream>>>(Abuf, Wt2, S);
  epi_final<<<1024, 256, 0, stream>>>(S, adj, b2, g2, be2, rm2, rv2, gn_g,
                                      gn_b, gn_rm, gn_rv, out);
}

// Round 2
// 429.501 us; speedup vs baseline: 1.1733x; 1.1733x over previous
//
#include <hip/hip_runtime.h>
#include <cstdint>
#include <cstddef>

#define EPSV 1e-5f

typedef __bf16 bf16x8 __attribute__((ext_vector_type(8)));
typedef float f32x4 __attribute__((ext_vector_type(4)));

__device__ __forceinline__ unsigned short f2bf(float f) {
  unsigned int u = __float_as_uint(f);
  u += 0x7FFFu + ((u >> 16) & 1u);   // round-to-nearest-even
  return (unsigned short)(u >> 16);
}

__device__ __forceinline__ void async_copy16(const void* src, void* dst_lds) {
  __builtin_amdgcn_global_load_lds(
      (const __attribute__((address_space(1))) void*)src,
      (__attribute__((address_space(3))) void*)dst_lds, 16, 0, 0);
}

// ---------------- Kernel 1: feat_global = mean(x_global, hw) + BN ----------
__global__ __launch_bounds__(256) void kmean(
    const float* __restrict__ x, const float* __restrict__ g,
    const float* __restrict__ bb, const float* __restrict__ rm,
    const float* __restrict__ rv, float* __restrict__ out) {
  int gw = blockIdx.x * 4 + (threadIdx.x >> 6);   // (b,c) pair per wave
  int lane = threadIdx.x & 63;
  float4 v = ((const float4*)(x + (size_t)gw * 256))[lane];
  float s = v.x + v.y + v.z + v.w;
#pragma unroll
  for (int o = 32; o > 0; o >>= 1) s += __shfl_xor(s, o, 64);
  if (lane == 0) {
    int b = gw >> 11, c = gw & 2047;
    float m = s * (1.f / 256.f);
    out[(size_t)b * 43008 + c] =
        (m - rm[c]) / sqrtf(rv[c] + EPSV) * g[c] + bb[c];
  }
}

// ---------------- Kernel 2: mask downsample, counts, drop ------------------
__global__ __launch_bounds__(256) void kmask(
    const int* __restrict__ mask, int* __restrict__ partid,
    float* __restrict__ invden, int* __restrict__ dropm1) {
  int b = blockIdx.x;
  int t = threadIdx.x;
  int h = t >> 4, w = t & 15;
  int m = mask[(size_t)b * 65536 + h * 4096 + w * 16];  // [b,0,h*16,w*16]
  partid[b * 256 + t] = m;
  __shared__ int cnt[10];
  if (t < 10) cnt[t] = 0;
  __syncthreads();
  atomicAdd(&cnt[m], 1);
  __syncthreads();
  if (t == 0) {
    int dp = 0;  // argmax(counts>0); all-false -> 0
    for (int p = 8; p >= 0; p--)
      if (cnt[p + 1] > 0) dp = p;
    dropm1[b] = dp;
  }
  if (t < 9) invden[b * 9 + t] = 1.f / ((float)cnt[t + 1] + 1e-8f);
}

// ---------------- Kernel 3: part-pooling via MFMA --------------------------
// mask_feat[b,p,c] = sum_s x[b,c,s]*onehot[s,p] * invden.
// self_feat == mask_feat with row (drop-1) zeroed.
// Block: (b, 64-channel chunk). A = x[64c x 256s] bf16 in LDS (pad 264),
// B = onehot[16p x 256s] bf16 in LDS. One 16x16x32 MFMA chain per wave.
__global__ __launch_bounds__(256) void kpool_mfma(
    const float* __restrict__ x, const int* __restrict__ partid,
    const float* __restrict__ invden, const int* __restrict__ dropm1,
    unsigned short* __restrict__ Abuf) {
  __shared__ unsigned short As[64 * 264];
  __shared__ unsigned short Bs[16 * 264];
  __shared__ int pid[256];
  const int t = threadIdx.x;
  const int b = blockIdx.y;
  const int c0 = blockIdx.x * 64;

  pid[t] = partid[b * 256 + t];

  const float4* xg = (const float4*)(x + ((size_t)(b * 2048 + c0)) * 256);
#pragma unroll
  for (int it = 0; it < 16; it++) {
    int idx = t + it * 256;          // 0..4095 float4s
    float4 v = xg[idx];
    int row = idx >> 6, sc = (idx & 63) * 4;
    ushort4 h;
    h.x = f2bf(v.x); h.y = f2bf(v.y); h.z = f2bf(v.z); h.w = f2bf(v.w);
    *(ushort4*)&As[row * 264 + sc] = h;
  }
  __syncthreads();
  // build onehot B: 16 p-rows x 256 s, 16 entries per thread
  {
    int p = t >> 4, s0 = (t & 15) * 16;
#pragma unroll
    for (int j = 0; j < 16; j++)
      Bs[p * 264 + s0 + j] =
          (pid[s0 + j] == p + 1) ? (unsigned short)0x3F80 : (unsigned short)0;
  }
  __syncthreads();

  const int wave = t >> 6;
  const int l16 = t & 15;
  const int quad = (t & 63) >> 4;
  f32x4 acc = (f32x4){0.f, 0.f, 0.f, 0.f};
#pragma unroll
  for (int ks = 0; ks < 8; ks++) {
    bf16x8 a = *(const bf16x8*)&As[(wave * 16 + l16) * 264 + ks * 32 + quad * 8];
    bf16x8 bf = *(const bf16x8*)&Bs[l16 * 264 + ks * 32 + quad * 8];
    acc = __builtin_amdgcn_mfma_f32_16x16x32_bf16(a, bf, acc, 0, 0, 0);
  }

  if (l16 < 9) {
    int p = l16;
    float inv = invden[b * 9 + p];
    int dm1 = dropm1[b];
    int cbase = c0 + wave * 16 + quad * 4;   // 4 consecutive channels
    ushort4 hm;
    hm.x = f2bf(acc[0] * inv);
    hm.y = f2bf(acc[1] * inv);
    hm.z = f2bf(acc[2] * inv);
    hm.w = f2bf(acc[3] * inv);
    ushort4 hs = (p == dm1) ? (ushort4){0, 0, 0, 0} : hm;
    *(ushort4*)&Abuf[(size_t)(b * 9 + p) * 2048 + cbase] = hm;
    *(ushort4*)&Abuf[(size_t)((64 + b) * 9 + p) * 2048 + cbase] = hs;
  }
}

// ---------------- Kernel 4: W (KxN fp32) -> Wt (NxK bf16), both weights ----
__global__ __launch_bounds__(256) void ktranspose(
    const float* __restrict__ W1, const float* __restrict__ W2,
    unsigned short* __restrict__ Wt1, unsigned short* __restrict__ Wt2) {
  const float* W = blockIdx.z ? W2 : W1;
  unsigned short* Wt = blockIdx.z ? Wt2 : Wt1;
  __shared__ float tile[32][33];
  int tx = threadIdx.x & 31;
  int ty = threadIdx.x >> 5;  // 0..7
  int k0 = blockIdx.y * 32;
  int n0 = blockIdx.x * 32;
#pragma unroll
  for (int i = 0; i < 32; i += 8)
    tile[ty + i][tx] = W[(size_t)(k0 + ty + i) * 2048 + n0 + tx];
  __syncthreads();
#pragma unroll
  for (int i = 0; i < 32; i += 8)
    Wt[(size_t)(n0 + ty + i) * 2048 + k0 + tx] = f2bf(tile[tx][ty + i]);
}

// ---------------- GEMM: S[M,N] = A[M,K] @ Wt[N,K]^T  (bf16 MFMA) -----------
// M=1152, N=K=2048.  128x128 tile, BK=32, 4 waves of 64x64, split-K=2.
#define GK 2048
__global__ __launch_bounds__(256) void gemm_bf16(
    const unsigned short* __restrict__ A, const unsigned short* __restrict__ Bt,
    float* __restrict__ S) {
  __shared__ unsigned short As[128 * 32];
  __shared__ unsigned short Bs[128 * 32];
  const int tid = threadIdx.x;
  const int lane = tid & 63;
  const int wave = tid >> 6;
  const int wm = (wave >> 1) << 6;
  const int wn = (wave & 1) << 6;
  const int quad = lane >> 4;
  const int l16 = lane & 15;
  const int by = blockIdx.y;
  const int bx = blockIdx.x;
  const int kz = blockIdx.z;

  const unsigned short* Ag = A + (size_t)by * 128 * GK;
  const unsigned short* Bg = Bt + (size_t)bx * 128 * GK;
  S += (size_t)kz * 1152 * 2048;

  f32x4 acc[4][4];
#pragma unroll
  for (int i = 0; i < 4; i++)
#pragma unroll
    for (int j = 0; j < 4; j++) acc[i][j] = (f32x4){0.f, 0.f, 0.f, 0.f};

  const int seg0 = tid, seg1 = tid + 256;
  const int r0 = seg0 >> 2, c0 = (seg0 & 3) * 8;
  const int r1 = seg1 >> 2, c1 = (seg1 & 3) * 8;

  const int kbeg = kz * (GK / 2), kend = kbeg + (GK / 2);
  for (int kk = kbeg; kk < kend; kk += 32) {
    __syncthreads();  // prev iter's LDS reads done
    async_copy16(Ag + (size_t)r0 * GK + kk + c0, &As[seg0 * 8]);
    async_copy16(Ag + (size_t)r1 * GK + kk + c1, &As[seg1 * 8]);
    async_copy16(Bg + (size_t)r0 * GK + kk + c0, &Bs[seg0 * 8]);
    async_copy16(Bg + (size_t)r1 * GK + kk + c1, &Bs[seg1 * 8]);
    asm volatile("s_waitcnt vmcnt(0)" ::: "memory");
    __syncthreads();

    bf16x8 af[4], bfr[4];
#pragma unroll
    for (int i = 0; i < 4; i++)
      af[i] = *(const bf16x8*)&As[(wm + i * 16 + l16) * 32 + quad * 8];
#pragma unroll
    for (int j = 0; j < 4; j++)
      bfr[j] = *(const bf16x8*)&Bs[(wn + j * 16 + l16) * 32 + quad * 8];
#pragma unroll
    for (int i = 0; i < 4; i++)
#pragma unroll
      for (int j = 0; j < 4; j++)
        acc[i][j] = __builtin_amdgcn_mfma_f32_16x16x32_bf16(af[i], bfr[j],
                                                            acc[i][j], 0, 0, 0);
  }

#pragma unroll
  for (int i = 0; i < 4; i++)
#pragma unroll
    for (int j = 0; j < 4; j++)
#pragma unroll
      for (int r = 0; r < 4; r++) {
        int m = by * 128 + wm + i * 16 + quad * 4 + r;
        int n = bx * 128 + wn + j * 16 + l16;
        S[(size_t)m * 2048 + n] = acc[i][j][r];
      }
}

// ---------------- Epilogue 1: adj-mix + bias + BN + ReLU -> A2 (bf16) ------
__global__ __launch_bounds__(256) void epi_mid(
    const float* __restrict__ S0, const float* __restrict__ S1,
    const float* __restrict__ adj, const float* __restrict__ bias,
    const float* __restrict__ g, const float* __restrict__ be,
    const float* __restrict__ rm, const float* __restrict__ rv,
    unsigned short* __restrict__ Aout) {
  int idx = blockIdx.x * 256 + threadIdx.x;  // over 128*2048
  int d = idx & 2047;
  int bb = idx >> 11;
  int b = bb & 63;
  float s[9];
#pragma unroll
  for (int q = 0; q < 9; q++) {
    size_t off = (size_t)(bb * 9 + q) * 2048 + d;
    s[q] = S0[off] + S1[off];
  }
#pragma unroll
  for (int p = 0; p < 9; p++) {
    float o = bias[d];
#pragma unroll
    for (int q = 0; q < 9; q++) o += adj[b * 81 + p * 9 + q] * s[q];
    int f = p * 2048 + d;
    float v = (o - rm[f]) / sqrtf(rv[f] + EPSV) * g[f] + be[f];
    v = fmaxf(v, 0.f);
    Aout[(size_t)(bb * 9 + p) * 2048 + d] = f2bf(v);
  }
}

// ---------------- Epilogue 2: adj-mix + BN + ReLU -> cats, means, BN -------
__global__ __launch_bounds__(256) void epi_final(
    const float* __restrict__ S0, const float* __restrict__ S1,
    const float* __restrict__ adj, const float* __restrict__ bias,
    const float* __restrict__ g, const float* __restrict__ be,
    const float* __restrict__ rm, const float* __restrict__ rv,
    const float* __restrict__ gn_g, const float* __restrict__ gn_b,
    const float* __restrict__ gn_rm, const float* __restrict__ gn_rv,
    float* __restrict__ out) {
  int idx = blockIdx.x * 256 + threadIdx.x;
  int d = idx & 2047;
  int bb = idx >> 11;
  int b = bb & 63;
  bool selfb = bb >= 64;
  float s[9];
#pragma unroll
  for (int q = 0; q < 9; q++) {
    size_t off = (size_t)(bb * 9 + q) * 2048 + d;
    s[q] = S0[off] + S1[off];
  }
  float* orow = out + (size_t)b * 43008;
  size_t catbase = selfb ? 24576 : 6144;
  float mean = 0.f;
#pragma unroll
  for (int p = 0; p < 9; p++) {
    float o = bias[d];
#pragma unroll
    for (int q = 0; q < 9; q++) o += adj[b * 81 + p * 9 + q] * s[q];
    int f = p * 2048 + d;
    float v = (o - rm[f]) / sqrtf(rv[f] + EPSV) * g[f] + be[f];
    v = fmaxf(v, 0.f);
    mean += v;
    orow[catbase + f] = v;
  }
  mean *= (1.f / 9.f);
  orow[(selfb ? 4096 : 2048) + d] =
      (mean - gn_rm[d]) / sqrtf(gn_rv[d] + EPSV) * gn_g[d] + gn_b[d];
}

extern "C" void kernel_launch(void* const* d_in, const int* in_sizes, int n_in,
                              void* d_out, int out_size, void* d_ws,
                              size_t ws_size, hipStream_t stream) {
  const float* x_global = (const float*)d_in[0];
  const float* x_gcn = (const float*)d_in[1];
  const int* mask = (const int*)d_in[2];
  const float* adj = (const float*)d_in[3];
  const float* W1 = (const float*)d_in[4];
  const float* b1 = (const float*)d_in[5];
  const float* g1 = (const float*)d_in[6];
  const float* be1 = (const float*)d_in[7];
  const float* rm1 = (const float*)d_in[8];
  const float* rv1 = (const float*)d_in[9];
  const float* W2 = (const float*)d_in[10];
  const float* b2 = (const float*)d_in[11];
  const float* g2 = (const float*)d_in[12];
  const float* be2 = (const float*)d_in[13];
  const float* rm2 = (const float*)d_in[14];
  const float* rv2 = (const float*)d_in[15];
  const float* gb_g = (const float*)d_in[16];
  const float* gb_b = (const float*)d_in[17];
  const float* gb_rm = (const float*)d_in[18];
  const float* gb_rv = (const float*)d_in[19];
  const float* gn_g = (const float*)d_in[20];
  const float* gn_b = (const float*)d_in[21];
  const float* gn_rm = (const float*)d_in[22];
  const float* gn_rv = (const float*)d_in[23];
  float* out = (float*)d_out;

  char* ws = (char*)d_ws;
  int* partid = (int*)(ws);                       // 64*256*4      = 65536
  float* invden = (float*)(ws + 65536);           // 576*4         = 2304
  int* dropm1 = (int*)(ws + 67840);               // 64*4
  unsigned short* Abuf = (unsigned short*)(ws + 131072);           // 4.7MB
  unsigned short* Wt1 = (unsigned short*)(ws + 131072 + 4718592);  // 8MB
  unsigned short* Wt2 =
      (unsigned short*)(ws + 131072 + 4718592 + 8388608);          // 8MB
  float* S0 = (float*)(ws + 131072 + 4718592 + 2 * 8388608);       // 9.4MB
  float* S1 = S0 + (size_t)1152 * 2048;                            // 9.4MB

  ktranspose<<<dim3(64, 64, 2), 256, 0, stream>>>(W1, W2, Wt1, Wt2);
  kmean<<<32768, 256, 0, stream>>>(x_global, gb_g, gb_b, gb_rm, gb_rv, out);
  kmask<<<64, 256, 0, stream>>>(mask, partid, invden, dropm1);
  kpool_mfma<<<dim3(32, 64), 256, 0, stream>>>(x_gcn, partid, invden, dropm1,
                                               Abuf);
  gemm_bf16<<<dim3(16, 9, 2), 256, 0, stream>>>(Abuf, Wt1, S0);
  epi_mid<<<1024, 256, 0, stream>>>(S0, S1, adj, b1, g1, be1, rm1, rv1, Abuf);
  gemm_bf16<<<dim3(16, 9, 2), 256, 0, stream>>>(Abuf, Wt2, S0);
  epi_final<<<1024, 256, 0, stream>>>(S0, S1, adj, b2, g2, be2, rm2, rv2, gn_g,
                                      gn_b, gn_rm, gn_rv, out);
}

// Round 3
// 411.081 us; speedup vs baseline: 1.2259x; 1.0448x over previous
//
#include <hip/hip_runtime.h>
#include <cstdint>
#include <cstddef>

#define EPSV 1e-5f

typedef __bf16 bf16x8 __attribute__((ext_vector_type(8)));
typedef float f32x4 __attribute__((ext_vector_type(4)));

__device__ __forceinline__ unsigned short f2bf(float f) {
  unsigned int u = __float_as_uint(f);
  u += 0x7FFFu + ((u >> 16) & 1u);   // round-to-nearest-even
  return (unsigned short)(u >> 16);
}

__device__ __forceinline__ void async_copy16(const void* src, void* dst_lds) {
  __builtin_amdgcn_global_load_lds(
      (const __attribute__((address_space(1))) void*)src,
      (__attribute__((address_space(3))) void*)dst_lds, 16, 0, 0);
}

// ---------------- prep: weight transpose + global-mean BN + mask stats -----
// blocks [0,8192): transpose W1/W2 (fp32 KxN) -> Wt (bf16 NxK)
// blocks [8192,40960): feat_global = mean(x_global,hw) + BN -> out[:, :2048]
// blocks [40960,41024): mask downsample / counts / drop
__global__ __launch_bounds__(256) void prep(
    const float* __restrict__ W1, const float* __restrict__ W2,
    unsigned short* __restrict__ Wt1, unsigned short* __restrict__ Wt2,
    const float* __restrict__ xg, const float* __restrict__ gb_g,
    const float* __restrict__ gb_b, const float* __restrict__ gb_rm,
    const float* __restrict__ gb_rv, float* __restrict__ out,
    const int* __restrict__ mask, int* __restrict__ partid,
    float* __restrict__ invden, int* __restrict__ dropm1) {
  int blk = blockIdx.x;
  if (blk < 8192) {
    int z = blk >> 12;
    int rem = blk & 4095;
    int by = rem >> 6, bx = rem & 63;
    const float* W = z ? W2 : W1;
    unsigned short* Wt = z ? Wt2 : Wt1;
    __shared__ float tile[32][33];
    int tx = threadIdx.x & 31;
    int ty = threadIdx.x >> 5;  // 0..7
    int k0 = by * 32, n0 = bx * 32;
#pragma unroll
    for (int i = 0; i < 32; i += 8)
      tile[ty + i][tx] = W[(size_t)(k0 + ty + i) * 2048 + n0 + tx];
    __syncthreads();
#pragma unroll
    for (int i = 0; i < 32; i += 8)
      Wt[(size_t)(n0 + ty + i) * 2048 + k0 + tx] = f2bf(tile[tx][ty + i]);
  } else if (blk < 40960) {
    int gw = (blk - 8192) * 4 + (threadIdx.x >> 6);  // (b,c) pair per wave
    int lane = threadIdx.x & 63;
    float4 v = ((const float4*)(xg + (size_t)gw * 256))[lane];
    float s = v.x + v.y + v.z + v.w;
#pragma unroll
    for (int o = 32; o > 0; o >>= 1) s += __shfl_xor(s, o, 64);
    if (lane == 0) {
      int b = gw >> 11, c = gw & 2047;
      float m = s * (1.f / 256.f);
      out[(size_t)b * 43008 + c] =
          (m - gb_rm[c]) / sqrtf(gb_rv[c] + EPSV) * gb_g[c] + gb_b[c];
    }
  } else {
    int b = blk - 40960;
    int t = threadIdx.x;
    int h = t >> 4, w = t & 15;
    int m = mask[(size_t)b * 65536 + h * 4096 + w * 16];
    partid[b * 256 + t] = m;
    __shared__ int cnt[10];
    if (t < 10) cnt[t] = 0;
    __syncthreads();
    atomicAdd(&cnt[m], 1);
    __syncthreads();
    if (t == 0) {
      int dp = 0;
      for (int p = 8; p >= 0; p--)
        if (cnt[p + 1] > 0) dp = p;
      dropm1[b] = dp;
    }
    if (t < 9) invden[b * 9 + t] = 1.f / ((float)cnt[t + 1] + 1e-8f);
  }
}

// ---------------- part-pooling via MFMA ------------------------------------
__global__ __launch_bounds__(256) void kpool_mfma(
    const float* __restrict__ x, const int* __restrict__ partid,
    const float* __restrict__ invden, const int* __restrict__ dropm1,
    unsigned short* __restrict__ Abuf) {
  __shared__ unsigned short As[64 * 264];
  __shared__ unsigned short Bs[16 * 264];
  __shared__ int pid[256];
  const int t = threadIdx.x;
  const int b = blockIdx.y;
  const int c0 = blockIdx.x * 64;

  pid[t] = partid[b * 256 + t];

  const float4* xgp = (const float4*)(x + ((size_t)(b * 2048 + c0)) * 256);
#pragma unroll
  for (int it = 0; it < 16; it++) {
    int idx = t + it * 256;
    float4 v = xgp[idx];
    int row = idx >> 6, sc = (idx & 63) * 4;
    ushort4 h;
    h.x = f2bf(v.x); h.y = f2bf(v.y); h.z = f2bf(v.z); h.w = f2bf(v.w);
    *(ushort4*)&As[row * 264 + sc] = h;
  }
  __syncthreads();
  {
    int p = t >> 4, s0 = (t & 15) * 16;
#pragma unroll
    for (int j = 0; j < 16; j++)
      Bs[p * 264 + s0 + j] =
          (pid[s0 + j] == p + 1) ? (unsigned short)0x3F80 : (unsigned short)0;
  }
  __syncthreads();

  const int wave = t >> 6;
  const int l16 = t & 15;
  const int quad = (t & 63) >> 4;
  f32x4 acc = (f32x4){0.f, 0.f, 0.f, 0.f};
#pragma unroll
  for (int ks = 0; ks < 8; ks++) {
    bf16x8 a = *(const bf16x8*)&As[(wave * 16 + l16) * 264 + ks * 32 + quad * 8];
    bf16x8 bf = *(const bf16x8*)&Bs[l16 * 264 + ks * 32 + quad * 8];
    acc = __builtin_amdgcn_mfma_f32_16x16x32_bf16(a, bf, acc, 0, 0, 0);
  }

  if (l16 < 9) {
    int p = l16;
    float inv = invden[b * 9 + p];
    int dm1 = dropm1[b];
    int cbase = c0 + wave * 16 + quad * 4;
    ushort4 hm;
    hm.x = f2bf(acc[0] * inv);
    hm.y = f2bf(acc[1] * inv);
    hm.z = f2bf(acc[2] * inv);
    hm.w = f2bf(acc[3] * inv);
    ushort4 hs = (p == dm1) ? (ushort4){0, 0, 0, 0} : hm;
    *(ushort4*)&Abuf[(size_t)(b * 9 + p) * 2048 + cbase] = hm;
    *(ushort4*)&Abuf[(size_t)((64 + b) * 9 + p) * 2048 + cbase] = hs;
  }
}

// ---------------- GEMM: S[M,N] = A[M,K] @ Wt[N,K]^T  (bf16 MFMA) -----------
// 128x128 tile, BK=64 double-buffered, split-K=4 (grid 16x9x4 = 576 blocks).
// LDS column-blocks XOR-swizzled by (row&7) to kill b128 bank conflicts;
// swizzle applied on the *global source* address so global_load_lds keeps
// its lane-contiguous LDS mapping.
#define GK 2048
#define SPART (1152 * 2048)
__global__ __launch_bounds__(256) void gemm_db(
    const unsigned short* __restrict__ A, const unsigned short* __restrict__ Bt,
    float* __restrict__ S) {
  __shared__ unsigned short As[2][128 * 64];
  __shared__ unsigned short Bs[2][128 * 64];
  const int tid = threadIdx.x;
  const int lane = tid & 63;
  const int wave = tid >> 6;
  const int wm = (wave >> 1) << 6;
  const int wn = (wave & 1) << 6;
  const int quad = lane >> 4;
  const int l16 = lane & 15;
  const int by = blockIdx.y;
  const int bx = blockIdx.x;
  const int kz = blockIdx.z;

  const unsigned short* Ag = A + (size_t)by * 128 * GK;
  const unsigned short* Bg = Bt + (size_t)bx * 128 * GK;
  S += (size_t)kz * SPART;

  f32x4 acc[4][4];
#pragma unroll
  for (int i = 0; i < 4; i++)
#pragma unroll
    for (int j = 0; j < 4; j++) acc[i][j] = (f32x4){0.f, 0.f, 0.f, 0.f};

  // staging: 1024 16B-slots per array, 4 per thread. slot idx holds global
  // column-block (c' ^ (r&7)) of row r, where r=idx>>3, c'=idx&7.
  int srow[4], scol[4];
#pragma unroll
  for (int s = 0; s < 4; s++) {
    int idx = tid + s * 256;
    srow[s] = idx >> 3;
    scol[s] = ((idx & 7) ^ (srow[s] & 7)) * 8;
  }

  const int kbeg = kz * 512;

#define STAGE(buf, kk)                                                        \
  do {                                                                        \
    _Pragma("unroll") for (int s = 0; s < 4; s++) {                           \
      int idx = tid + s * 256;                                                \
      async_copy16(Ag + (size_t)srow[s] * GK + (kk) + scol[s],                \
                   &As[buf][idx * 8]);                                        \
    }                                                                         \
    _Pragma("unroll") for (int s = 0; s < 4; s++) {                           \
      int idx = tid + s * 256;                                                \
      async_copy16(Bg + (size_t)srow[s] * GK + (kk) + scol[s],                \
                   &Bs[buf][idx * 8]);                                        \
    }                                                                         \
  } while (0)

  STAGE(0, kbeg);
  asm volatile("s_waitcnt vmcnt(0)" ::: "memory");
  __syncthreads();

  for (int it = 0; it < 8; it++) {
    const int cur = it & 1;
    if (it < 7) STAGE(cur ^ 1, kbeg + (it + 1) * 64);

#pragma unroll
    for (int ks = 0; ks < 2; ks++) {
      bf16x8 af[4], bfr[4];
#pragma unroll
      for (int i = 0; i < 4; i++) {
        int row = wm + i * 16 + l16;
        int slot = row * 8 + ((ks * 4 + quad) ^ (row & 7));
        af[i] = *(const bf16x8*)&As[cur][slot * 8];
      }
#pragma unroll
      for (int j = 0; j < 4; j++) {
        int row = wn + j * 16 + l16;
        int slot = row * 8 + ((ks * 4 + quad) ^ (row & 7));
        bfr[j] = *(const bf16x8*)&Bs[cur][slot * 8];
      }
#pragma unroll
      for (int i = 0; i < 4; i++)
#pragma unroll
        for (int j = 0; j < 4; j++)
          acc[i][j] = __builtin_amdgcn_mfma_f32_16x16x32_bf16(
              af[i], bfr[j], acc[i][j], 0, 0, 0);
    }

    if (it < 7) {
      asm volatile("s_waitcnt vmcnt(0)" ::: "memory");
      __syncthreads();
    }
  }

#pragma unroll
  for (int i = 0; i < 4; i++)
#pragma unroll
    for (int j = 0; j < 4; j++)
#pragma unroll
      for (int r = 0; r < 4; r++) {
        int m = by * 128 + wm + i * 16 + quad * 4 + r;
        int n = bx * 128 + wn + j * 16 + l16;
        S[(size_t)m * 2048 + n] = acc[i][j][r];
      }
}

// ---------------- Epilogue 1: adj-mix + bias + BN + ReLU -> A2 (bf16) ------
__global__ __launch_bounds__(256) void epi_mid(
    const float* __restrict__ S, const float* __restrict__ adj,
    const float* __restrict__ bias, const float* __restrict__ g,
    const float* __restrict__ be, const float* __restrict__ rm,
    const float* __restrict__ rv, unsigned short* __restrict__ Aout) {
  int idx = blockIdx.x * 256 + threadIdx.x;  // over 128*2048
  int d = idx & 2047;
  int bb = idx >> 11;
  int b = bb & 63;
  float s[9];
#pragma unroll
  for (int q = 0; q < 9; q++) {
    size_t off = (size_t)(bb * 9 + q) * 2048 + d;
    s[q] = S[off] + S[off + SPART] + S[off + 2 * SPART] + S[off + 3 * SPART];
  }
#pragma unroll
  for (int p = 0; p < 9; p++) {
    float o = bias[d];
#pragma unroll
    for (int q = 0; q < 9; q++) o += adj[b * 81 + p * 9 + q] * s[q];
    int f = p * 2048 + d;
    float v = (o - rm[f]) / sqrtf(rv[f] + EPSV) * g[f] + be[f];
    v = fmaxf(v, 0.f);
    Aout[(size_t)(bb * 9 + p) * 2048 + d] = f2bf(v);
  }
}

// ---------------- Epilogue 2: adj-mix + BN + ReLU -> cats, means, BN -------
__global__ __launch_bounds__(256) void epi_final(
    const float* __restrict__ S, const float* __restrict__ adj,
    const float* __restrict__ bias, const float* __restrict__ g,
    const float* __restrict__ be, const float* __restrict__ rm,
    const float* __restrict__ rv, const float* __restrict__ gn_g,
    const float* __restrict__ gn_b, const float* __restrict__ gn_rm,
    const float* __restrict__ gn_rv, float* __restrict__ out) {
  int idx = blockIdx.x * 256 + threadIdx.x;
  int d = idx & 2047;
  int bb = idx >> 11;
  int b = bb & 63;
  bool selfb = bb >= 64;
  float s[9];
#pragma unroll
  for (int q = 0; q < 9; q++) {
    size_t off = (size_t)(bb * 9 + q) * 2048 + d;
    s[q] = S[off] + S[off + SPART] + S[off + 2 * SPART] + S[off + 3 * SPART];
  }
  float* orow = out + (size_t)b * 43008;
  size_t catbase = selfb ? 24576 : 6144;
  float mean = 0.f;
#pragma unroll
  for (int p = 0; p < 9; p++) {
    float o = bias[d];
#pragma unroll
    for (int q = 0; q < 9; q++) o += adj[b * 81 + p * 9 + q] * s[q];
    int f = p * 2048 + d;
    float v = (o - rm[f]) / sqrtf(rv[f] + EPSV) * g[f] + be[f];
    v = fmaxf(v, 0.f);
    mean += v;
    orow[catbase + f] = v;
  }
  mean *= (1.f / 9.f);
  orow[(selfb ? 4096 : 2048) + d] =
      (mean - gn_rm[d]) / sqrtf(gn_rv[d] + EPSV) * gn_g[d] + gn_b[d];
}

extern "C" void kernel_launch(void* const* d_in, const int* in_sizes, int n_in,
                              void* d_out, int out_size, void* d_ws,
                              size_t ws_size, hipStream_t stream) {
  const float* x_global = (const float*)d_in[0];
  const float* x_gcn = (const float*)d_in[1];
  const int* mask = (const int*)d_in[2];
  const float* adj = (const float*)d_in[3];
  const float* W1 = (const float*)d_in[4];
  const float* b1 = (const float*)d_in[5];
  const float* g1 = (const float*)d_in[6];
  const float* be1 = (const float*)d_in[7];
  const float* rm1 = (const float*)d_in[8];
  const float* rv1 = (const float*)d_in[9];
  const float* W2 = (const float*)d_in[10];
  const float* b2 = (const float*)d_in[11];
  const float* g2 = (const float*)d_in[12];
  const float* be2 = (const float*)d_in[13];
  const float* rm2 = (const float*)d_in[14];
  const float* rv2 = (const float*)d_in[15];
  const float* gb_g = (const float*)d_in[16];
  const float* gb_b = (const float*)d_in[17];
  const float* gb_rm = (const float*)d_in[18];
  const float* gb_rv = (const float*)d_in[19];
  const float* gn_g = (const float*)d_in[20];
  const float* gn_b = (const float*)d_in[21];
  const float* gn_rm = (const float*)d_in[22];
  const float* gn_rv = (const float*)d_in[23];
  float* out = (float*)d_out;

  char* ws = (char*)d_ws;
  int* partid = (int*)(ws);                            // 64*256*4 = 65536
  float* invden = (float*)(ws + 65536);                // 576*4
  int* dropm1 = (int*)(ws + 67840);                    // 64*4
  unsigned short* Abuf = (unsigned short*)(ws + 131072);           // 4.5MB
  unsigned short* Wt1 = (unsigned short*)(ws + 4849664);           // 8MB
  unsigned short* Wt2 = (unsigned short*)(ws + 13238272);          // 8MB
  float* S = (float*)(ws + 21626880);                  // 4 x 9.4MB partials

  prep<<<41024, 256, 0, stream>>>(W1, W2, Wt1, Wt2, x_global, gb_g, gb_b,
                                  gb_rm, gb_rv, out, mask, partid, invden,
                                  dropm1);
  kpool_mfma<<<dim3(32, 64), 256, 0, stream>>>(x_gcn, partid, invden, dropm1,
                                               Abuf);
  gemm_db<<<dim3(16, 9, 4), 256, 0, stream>>>(Abuf, Wt1, S);
  epi_mid<<<1024, 256, 0, stream>>>(S, adj, b1, g1, be1, rm1, rv1, Abuf);
  gemm_db<<<dim3(16, 9, 4), 256, 0, stream>>>(Abuf, Wt2, S);
  epi_final<<<1024, 256, 0, stream>>>(S, adj, b2, g2, be2, rm2, rv2, gn_g,
                                      gn_b, gn_rm, gn_rv, out);
}